// Round 4
// baseline (119.015 us; speedup 1.0000x reference)
//
#include <hip/hip_runtime.h>
#include <math.h>

#define TOTAL 200      // distance bins (STOP/DELTA)
#define TB    128      // B-tile columns per block (small -> ~9 blocks/CU, wave-cap bound)
#define BLK   256      // threads per block = A rows per block
#define NH    8        // sub-histograms: 4 waves x lane parity

// ---------------------------------------------------------------------------
// prep: scale positions by real_size, pack float4{x,y,z,|p|^2} into ws;
// block 0 also zeros the 3 global histograms. Same-stream ordering makes this
// visible to rdf_hist.
// ---------------------------------------------------------------------------
__global__ void rdf_prep(const float* __restrict__ p0, const float* __restrict__ p1,
                         const float* __restrict__ rs,
                         float4* __restrict__ b0, float4* __restrict__ b1,
                         unsigned int* __restrict__ hist, int n0, int n1)
{
    const float sx = rs[0], sy = rs[1], sz = rs[2];
    int t = blockIdx.x * blockDim.x + threadIdx.x;
    if (t < n0) {
        float x = p0[t*3+0]*sx, y = p0[t*3+1]*sy, z = p0[t*3+2]*sz;
        b0[t] = make_float4(x, y, z, x*x + y*y + z*z);
    } else if (t < n0 + n1) {
        int u = t - n0;
        float x = p1[u*3+0]*sx, y = p1[u*3+1]*sy, z = p1[u*3+2]*sz;
        b1[u] = make_float4(x, y, z, x*x + y*y + z*z);
    }
    if (blockIdx.x == 0)
        for (int k = threadIdx.x; k < 3*TOTAL; k += BLK) hist[k] = 0;
}

// ---------------------------------------------------------------------------
// inner pair loop. Bs[j] is wave-uniform -> scalar load on the SMEM pipe, NOT
// the DS pipe. DIAG keeps only strict upper triangle: global col = colBase+j
// must exceed aIdx, i.e. j > ofs (ofs = aIdx - colBase; may be <0 or >=TB).
// ---------------------------------------------------------------------------
template<bool DIAG>
__device__ __forceinline__ void pair_loop(const float4* __restrict__ Bs,
                                          float ax, float ay, float az, float a2,
                                          unsigned int* __restrict__ mylh, int ofs)
{
    #pragma unroll 8
    for (int j = 0; j < TB; ++j) {
        float4 b  = Bs[j];
        float dot = ax*b.x + ay*b.y + az*b.z;
        float d2  = (a2 + b.w) - 2.0f*dot;                    // reference identity
        float v   = __builtin_amdgcn_sqrtf(fmaxf(d2, 0.0f)) * 20.0f; // 1 v_sqrt_f32
        bool ok   = (v < 200.0f);
        if (DIAG) ok = ok && (j > ofs);
        if (ok) atomicAdd(&mylh[(int)v], 1u);
    }
}

// ---------------------------------------------------------------------------
// pair-histogram kernel. Grid flattened over 3 pair types:
//   [0,p0)      : b0 x b0 self  -> hist 0   (upper triangle only, doubled)
//   [p0,p01)    : b0 x b1 cross -> hist 1   (serves [0][1] and [1][0])
//   [p01,total) : b1 x b1 self  -> hist 2   (upper triangle only, doubled)
// ---------------------------------------------------------------------------
__global__ __launch_bounds__(BLK) void rdf_hist(
    const float4* __restrict__ b0, const float4* __restrict__ b1,
    unsigned int* __restrict__ hist,
    int n0, int n1, int p0, int p01, int cb0, int cb1)
{
    __shared__ unsigned int lh[NH][TOTAL];

    int bid = blockIdx.x;
    const float4* Abase; const float4* Bbase;
    int nA, histIdx, nCols; bool self;
    if (bid < p0)       { Abase=b0; Bbase=b0; nA=n0; histIdx=0; self=true;  nCols=cb0; }
    else if (bid < p01) { Abase=b0; Bbase=b1; nA=n0; histIdx=1; self=false; nCols=cb1; bid -= p0; }
    else                { Abase=b1; Bbase=b1; nA=n1; histIdx=2; self=true;  nCols=cb1; bid -= p01; }
    int rb = bid / nCols;
    int cb = bid % nCols;

    const int rowBase = rb * BLK;
    const int colBase = cb * TB;
    if (self && (colBase + TB - 1) < rowBase) return;   // fully below diagonal
    const bool diag = self && (colBase < rowBase + BLK); // block straddles diagonal

    const int tid  = threadIdx.x;
    const int wave = tid >> 6;
    unsigned int* mylh = &lh[(wave << 1) | (tid & 1)][0];  // per-wave x parity

    for (int k = tid; k < NH*TOTAL; k += BLK) ((unsigned int*)lh)[k] = 0;
    __syncthreads();

    const int  aIdx   = rowBase + tid;
    const bool aValid = aIdx < nA;
    const float4* Bs  = Bbase + colBase;   // wave-uniform base

    if (aValid) {
        float4 a = Abase[aIdx];            // coalesced dwordx4
        if (diag) pair_loop<true >(Bs, a.x, a.y, a.z, a.w, mylh, aIdx - colBase);
        else      pair_loop<false>(Bs, a.x, a.y, a.z, a.w, mylh, 0);
    }
    __syncthreads();

    for (int k = tid; k < TOTAL; k += BLK) {
        unsigned int c = 0;
        #pragma unroll
        for (int h = 0; h < NH; ++h) c += lh[h][k];
        if (c) atomicAdd(&hist[histIdx*TOTAL + k], self ? 2u*c : c);
    }
}

// ---------------------------------------------------------------------------
// normalize: out[i][j][k] = count[i][j][k] + h_ij[k]/density/SLICE_VOL[k]/Na
// division order matches the reference exactly.
// ---------------------------------------------------------------------------
__global__ void rdf_final(const unsigned int* __restrict__ hist,
                          const float* __restrict__ count,
                          const float* __restrict__ rs,
                          float* __restrict__ out, int n0, int n1)
{
    int t = blockIdx.x * blockDim.x + threadIdx.x;
    if (t >= 2*2*TOTAL) return;
    int k = t % TOTAL;
    int j = (t / TOTAL) & 1;
    int i = t / (2*TOTAL);

    float vol = rs[0]*rs[1]*rs[2];
    int Na = (i == 0) ? n0 : n1;
    int Nb = (j == 0) ? n0 : n1;
    int hidx = (i == j) ? (i == 0 ? 0 : 2) : 1;

    float c = (float)hist[hidx*TOTAL + k];
    // SLICE_VOL computed in float64 then cast, matching numpy
    double sv  = ((0.025 + (double)k * 0.05) * 0.05) * 2.0 * M_PI * 3.0;
    float  svf = (float)sv;
    float  density = (float)Nb / vol;
    float  r = ((c / density) / svf) / (float)Na;
    out[t] = count[t] + r;
}

extern "C" void kernel_launch(void* const* d_in, const int* in_sizes, int n_in,
                              void* d_out, int out_size, void* d_ws, size_t ws_size,
                              hipStream_t stream) {
    const float* pos0  = (const float*)d_in[0];
    const float* pos1  = (const float*)d_in[1];
    const float* count = (const float*)d_in[2];
    const float* rs    = (const float*)d_in[3];
    float* out = (float*)d_out;

    int n0 = in_sizes[0] / 3;   // 4096
    int n1 = in_sizes[1] / 3;   // 8192

    // ws layout: [hist 3*200 u32][pad to 4KB][b0 scaled float4][b1 scaled float4]
    unsigned int* hist = (unsigned int*)d_ws;
    float4* b0 = (float4*)((char*)d_ws + 4096);
    float4* b1 = b0 + n0;

    int prepBlocks = (n0 + n1 + BLK - 1) / BLK;
    rdf_prep<<<prepBlocks, BLK, 0, stream>>>(pos0, pos1, rs, b0, b1, hist, n0, n1);

    int rb0 = (n0 + BLK - 1) / BLK;   // 16
    int rb1 = (n1 + BLK - 1) / BLK;   // 32
    int cb0 = (n0 + TB - 1) / TB;     // 32
    int cb1 = (n1 + TB - 1) / TB;     // 64
    int p0  = rb0 * cb0;              // self b0 blocks (512; lower tri exits)
    int p1  = rb0 * cb1;              // cross blocks   (1024, all active)
    int p2  = rb1 * cb1;              // self b1 blocks (2048; lower tri exits)

    rdf_hist<<<p0 + p1 + p2, BLK, 0, stream>>>(b0, b1, hist,
                                               n0, n1, p0, p0 + p1, cb0, cb1);

    rdf_final<<<(2*2*TOTAL + BLK - 1) / BLK, BLK, 0, stream>>>(hist, count, rs, out, n0, n1);
}

// Round 5
// 103.239 us; speedup vs baseline: 1.1528x; 1.1528x over previous
//
#include <hip/hip_runtime.h>
#include <math.h>

#define TOTAL 200      // distance bins (STOP/DELTA)
#define TB    32       // tile columns (small: balance granularity)
#define BLK   256      // threads per block = tile rows
#define NW    4        // waves per block
#define GRID  2048     // persistent blocks: 8/CU x 256 CU (wave-slot + LDS cap)
#define NR    16       // replicated global histograms (spread atomic chains)
#define RATIO (BLK/TB) // 8: cbMin(rb) = RATIO*rb for self-pair triangles

// ---------------------------------------------------------------------------
// prep: scale positions by real_size, pack float4{x,y,z,|p|^2}; zero the NR
// replicated global histograms. Same-stream ordering covers rdf_hist.
// ---------------------------------------------------------------------------
__global__ void rdf_prep(const float* __restrict__ p0, const float* __restrict__ p1,
                         const float* __restrict__ rs,
                         float4* __restrict__ b0, float4* __restrict__ b1,
                         unsigned int* __restrict__ ghist, int n0, int n1)
{
    const float sx = rs[0], sy = rs[1], sz = rs[2];
    int t = blockIdx.x * blockDim.x + threadIdx.x;
    if (t < n0) {
        float x = p0[t*3+0]*sx, y = p0[t*3+1]*sy, z = p0[t*3+2]*sz;
        b0[t] = make_float4(x, y, z, x*x + y*y + z*z);
    } else if (t < n0 + n1) {
        int u = t - n0;
        float x = p1[u*3+0]*sx, y = p1[u*3+1]*sy, z = p1[u*3+2]*sz;
        b1[u] = make_float4(x, y, z, x*x + y*y + z*z);
    }
    if (t < NR * 3 * TOTAL) ghist[t] = 0;   // 9600 words <= grid threads
}

// ---------------------------------------------------------------------------
// inner pair loop. Bs[j] is wave-uniform -> scalar load (SMEM pipe, not DS).
// DIAG keeps strict upper triangle: j > ofs (ofs = aIdx - colBase).
// ---------------------------------------------------------------------------
template<bool DIAG>
__device__ __forceinline__ void pair_loop(const float4* __restrict__ Bs,
                                          float ax, float ay, float az, float a2,
                                          unsigned int* __restrict__ mylh, int ofs)
{
    #pragma unroll 8
    for (int j = 0; j < TB; ++j) {
        float4 b  = Bs[j];
        float dot = ax*b.x + ay*b.y + az*b.z;
        float d2  = (a2 + b.w) - 2.0f*dot;                    // reference identity
        float v   = __builtin_amdgcn_sqrtf(fmaxf(d2, 0.0f)) * 20.0f; // 1 v_sqrt_f32
        bool ok   = (v < 200.0f);
        if (DIAG) ok = ok && (j > ofs);
        if (ok) atomicAdd(&mylh[(int)v], 1u);
    }
}

// ---------------------------------------------------------------------------
// persistent pair-histogram kernel. Compact tile list (triangle pre-applied):
//   [0,T0)   : b0 x b0 self  (rows0 x cb0, cb >= RATIO*rb) -> hist 0, doubled
//   [T0,T01) : b0 x b1 cross (rows0 x cb1, all)            -> hist 1
//   [T01,Tt) : b1 x b1 self  (rows1 x cb1, cb >= RATIO*rb) -> hist 2, doubled
// Each block takes a CONTIGUOUS chunk of tiles (L2 streaming + mostly 1 type),
// zeroes LDS hists once, flushes once to its replica. No per-tile barriers:
// LDS hists are [type][wave][parity] private.
// ---------------------------------------------------------------------------
__global__ __launch_bounds__(BLK) void rdf_hist(
    const float4* __restrict__ b0, const float4* __restrict__ b1,
    unsigned int* __restrict__ ghist,
    int n0, int n1, int T0, int T01, int Ttot,
    int cb0, int cb1, int rows0, int rows1)
{
    __shared__ unsigned int lh[3][NW][2][TOTAL];   // 19.2 KB -> 8 blocks/CU

    const int tid  = threadIdx.x;
    const int wave = tid >> 6;
    const int par  = tid & 1;

    // vectorized zero: 4800 words = 1200 uint4
    uint4* z = (uint4*)lh;
    for (int k = tid; k < 3*NW*2*TOTAL/4; k += BLK) z[k] = make_uint4(0,0,0,0);
    __syncthreads();

    const int gBeg = (int)(((long long)blockIdx.x       * Ttot) / GRID);
    const int gEnd = (int)(((long long)(blockIdx.x + 1) * Ttot) / GRID);

    for (int g = gBeg; g < gEnd; ++g) {
        // ---- decode tile id -> (type, rb, cb); all wave-uniform scalar math
        int type, rb, cb;
        if (g < T0) {
            type = 0; rb = 0;
            // offset(r) = cb0*r - (RATIO/2)*r*(r-1)
            while (rb + 1 < rows0 && (cb0*(rb+1) - (RATIO/2)*(rb+1)*rb) <= g) ++rb;
            cb = RATIO*rb + (g - (cb0*rb - (RATIO/2)*rb*(rb-1)));
        } else if (g < T01) {
            int u = g - T0; type = 1; rb = u / cb1; cb = u - rb*cb1;
        } else {
            int u = g - T01; type = 2; rb = 0;
            while (rb + 1 < rows1 && (cb1*(rb+1) - (RATIO/2)*(rb+1)*rb) <= u) ++rb;
            cb = RATIO*rb + (u - (cb1*rb - (RATIO/2)*rb*(rb-1)));
        }
        const float4* Ab = (type == 2) ? b1 : b0;
        const float4* Bb = (type == 0) ? b0 : b1;
        const int nA     = (type == 2) ? n1 : n0;

        const int rowBase = rb * BLK;
        const int colBase = cb * TB;
        const int aIdx    = rowBase + tid;

        float4 a = (aIdx < nA) ? Ab[aIdx]
                               : make_float4(0.f, 0.f, 0.f, 3.0e18f); // pad row -> no bins
        unsigned int* mylh = &lh[type][wave][par][0];
        const float4* Bs   = Bb + colBase;          // wave-uniform base

        const bool diag = (type != 1) && (colBase < rowBase + BLK); // straddles diagonal
        if (diag) pair_loop<true >(Bs, a.x, a.y, a.z, a.w, mylh, aIdx - colBase);
        else      pair_loop<false>(Bs, a.x, a.y, a.z, a.w, mylh, 0);
    }
    __syncthreads();

    // one flush per block to its replica; self-pair hists doubled (triangle)
    unsigned int* gh = ghist + (blockIdx.x & (NR - 1)) * (3 * TOTAL);
    for (int k = tid; k < 3 * TOTAL; k += BLK) {
        int type = k / TOTAL, bin = k - type * TOTAL;
        unsigned int c = 0;
        #pragma unroll
        for (int w = 0; w < NW; ++w)
            { c += lh[type][w][0][bin] + lh[type][w][1][bin]; }
        if (c) atomicAdd(&gh[k], (type == 1) ? c : 2u * c);
    }
}

// ---------------------------------------------------------------------------
// normalize: out[i][j][k] = count[i][j][k] + h_ij[k]/density/SLICE_VOL[k]/Na
// (sums the NR replicas; division order matches the reference exactly)
// ---------------------------------------------------------------------------
__global__ void rdf_final(const unsigned int* __restrict__ ghist,
                          const float* __restrict__ count,
                          const float* __restrict__ rs,
                          float* __restrict__ out, int n0, int n1)
{
    int t = blockIdx.x * blockDim.x + threadIdx.x;
    if (t >= 2*2*TOTAL) return;
    int k = t % TOTAL;
    int j = (t / TOTAL) & 1;
    int i = t / (2*TOTAL);

    float vol = rs[0]*rs[1]*rs[2];
    int Na = (i == 0) ? n0 : n1;
    int Nb = (j == 0) ? n0 : n1;
    int hidx = (i == j) ? (i == 0 ? 0 : 2) : 1;

    unsigned int c = 0;
    #pragma unroll
    for (int r = 0; r < NR; ++r) c += ghist[r*3*TOTAL + hidx*TOTAL + k];

    double sv  = ((0.025 + (double)k * 0.05) * 0.05) * 2.0 * M_PI * 3.0; // fp64 SLICE_VOL
    float  svf = (float)sv;
    float  density = (float)Nb / vol;
    float  r = (((float)c / density) / svf) / (float)Na;
    out[t] = count[t] + r;
}

extern "C" void kernel_launch(void* const* d_in, const int* in_sizes, int n_in,
                              void* d_out, int out_size, void* d_ws, size_t ws_size,
                              hipStream_t stream) {
    const float* pos0  = (const float*)d_in[0];
    const float* pos1  = (const float*)d_in[1];
    const float* count = (const float*)d_in[2];
    const float* rs    = (const float*)d_in[3];
    float* out = (float*)d_out;

    int n0 = in_sizes[0] / 3;   // 4096
    int n1 = in_sizes[1] / 3;   // 8192

    // ws layout: [ghist NR*3*200 u32 = 38.4KB][pad to 40KB][b0][b1]
    unsigned int* ghist = (unsigned int*)d_ws;
    float4* b0 = (float4*)((char*)d_ws + 40960);
    float4* b1 = b0 + n0;

    int prepBlocks = (n0 + n1 + BLK - 1) / BLK;   // 12288 threads >= 9600 hist words
    rdf_prep<<<prepBlocks, BLK, 0, stream>>>(pos0, pos1, rs, b0, b1, ghist, n0, n1);

    int rows0 = (n0 + BLK - 1) / BLK;   // 16
    int rows1 = (n1 + BLK - 1) / BLK;   // 32
    int cb0   = (n0 + TB - 1) / TB;     // 128
    int cb1   = (n1 + TB - 1) / TB;     // 256
    // triangle tile counts: sum_r (cols - RATIO*r) = cols*rows - (RATIO/2)*rows*(rows-1)
    int T0   = cb0*rows0 - (RATIO/2)*rows0*(rows0-1);   // 1088
    int Tc   = rows0*cb1;                               // 4096
    int T2   = cb1*rows1 - (RATIO/2)*rows1*(rows1-1);   // 4224
    int T01  = T0 + Tc;
    int Ttot = T01 + T2;                                // 9408

    rdf_hist<<<GRID, BLK, 0, stream>>>(b0, b1, ghist, n0, n1,
                                       T0, T01, Ttot, cb0, cb1, rows0, rows1);

    rdf_final<<<(2*2*TOTAL + BLK - 1) / BLK, BLK, 0, stream>>>(ghist, count, rs, out, n0, n1);
}